// Round 1
// baseline (106.665 us; speedup 1.0000x reference)
//
#include <hip/hip_runtime.h>
#include <stdint.h>

// Problem constants
#define T_TOK 32768   // B*S = 8*4096 tokens
#define NIN   1024
#define NOUT  1024

// GEMM tile
#define BM 128
#define BN 128
#define BK 128

typedef int v4i  __attribute__((ext_vector_type(4)));
typedef int v16i __attribute__((ext_vector_type(16)));

// ---------------------------------------------------------------------------
// global -> LDS direct staging, 16B per lane. Dest must be linear in lane
// order (HW uses wave-uniform base + lane*16); we pass base+lane*16 which is
// consistent with that rule.
// ---------------------------------------------------------------------------
__device__ __forceinline__ void gload_lds16(const void* g, void* l) {
  __builtin_amdgcn_global_load_lds(
      (const __attribute__((address_space(1))) unsigned int*)g,
      (__attribute__((address_space(3))) unsigned int*)l, 16, 0, 0);
}

// ---------------------------------------------------------------------------
// K0: weight arrives as int32 per harness convention ("integer -> const int*").
// Pack [NOUT][NIN] int32 -> int8 bytes in ws.
// ---------------------------------------------------------------------------
__global__ __launch_bounds__(256) void repack_w(const int* __restrict__ w,
                                                uint32_t* __restrict__ w8) {
  const int idx = blockIdx.x * 256 + threadIdx.x;      // packed-dword index
  const int4 v = ((const int4*)w)[idx];
  w8[idx] = (uint32_t)(v.x & 0xff) | ((uint32_t)(v.y & 0xff) << 8) |
            ((uint32_t)(v.z & 0xff) << 16) | ((uint32_t)(v.w & 0xff) << 24);
}

// ---------------------------------------------------------------------------
// K1: smoothquant + per-token symmetric int8 quantization.
// One wave per token (4 tokens / 256-thread block).
// lane i handles float4 elements at idx = j*64 + i  (coalesced 1KB/instr).
// ---------------------------------------------------------------------------
__global__ __launch_bounds__(256) void quant(const float* __restrict__ x,
                                             const float* __restrict__ sq,
                                             uint32_t* __restrict__ xq,
                                             float* __restrict__ ascale) {
  const int lane = threadIdx.x & 63;
  const int wid  = threadIdx.x >> 6;
  const int tok  = blockIdx.x * 4 + wid;
  const float4* xr = (const float4*)(x + (size_t)tok * NIN);
  const float4* sr = (const float4*)sq;

  float4 xs[4];
  float m = 0.f;
#pragma unroll
  for (int j = 0; j < 4; ++j) {
    const int idx = j * 64 + lane;
    float4 xv = xr[idx];
    const float4 sv = sr[idx];
    // v_rcp_f32 (~1ulp): IEEE div here would be VALU-bound; error impact on
    // rounding is ~1e-5 absolute at |q|<=127 -> negligible vs threshold.
    xv.x *= __builtin_amdgcn_rcpf(sv.x);
    xv.y *= __builtin_amdgcn_rcpf(sv.y);
    xv.z *= __builtin_amdgcn_rcpf(sv.z);
    xv.w *= __builtin_amdgcn_rcpf(sv.w);
    xs[j] = xv;
    m = fmaxf(m, fmaxf(fmaxf(fabsf(xv.x), fabsf(xv.y)),
                       fmaxf(fabsf(xv.z), fabsf(xv.w))));
  }
  // wave-wide allreduce max (64 lanes)
#pragma unroll
  for (int off = 1; off < 64; off <<= 1) m = fmaxf(m, __shfl_xor(m, off));

  const float a_scale = fmaxf(m * (1.f / 127.f), 1e-8f);
  if (lane == 0) ascale[tok] = a_scale;
  const float inv_a = __builtin_amdgcn_rcpf(a_scale);

  uint32_t* orow = xq + (size_t)tok * (NIN / 4);
#pragma unroll
  for (int j = 0; j < 4; ++j) {
    const int idx = j * 64 + lane;
    const float4 v = xs[j];
    const int q0 = (int)rintf(fminf(fmaxf(v.x * inv_a, -127.f), 127.f));
    const int q1 = (int)rintf(fminf(fmaxf(v.y * inv_a, -127.f), 127.f));
    const int q2 = (int)rintf(fminf(fmaxf(v.z * inv_a, -127.f), 127.f));
    const int q3 = (int)rintf(fminf(fmaxf(v.w * inv_a, -127.f), 127.f));
    orow[idx] = (uint32_t)(q0 & 0xff) | ((uint32_t)(q1 & 0xff) << 8) |
                ((uint32_t)(q2 & 0xff) << 16) | ((uint32_t)(q3 & 0xff) << 24);
  }
}

// ---------------------------------------------------------------------------
// K2: int8 GEMM  out[t][n] = (sum_k A8[t][k]*W8[n][k]) * ascale[t]*wscale[n] + bias[n]
// 128x128 tile, BK=128, 4 waves in 2x2, each wave 2x2 mfma_i32_32x32x32_i8.
// LDS layout: [row][8 chunks of 16B], chunk XOR-swizzled by (row&7) so
// ds_read_b128 fragment reads (32 lanes = 32 consecutive rows, fixed chunk)
// are bank-conflict-free. Staging writes LDS linearly via global_load_lds and
// applies the inverse (same) XOR on the *global source* chunk (rule #21).
// ---------------------------------------------------------------------------
__global__ __launch_bounds__(256) void w8a8_gemm(
    const int8_t* __restrict__ A8,      // [T_TOK][NIN]
    const int8_t* __restrict__ W8,      // [NOUT][NIN]
    const float* __restrict__ ascale,   // [T_TOK]
    const float* __restrict__ wclip,    // [NOUT]
    const float* __restrict__ bias,     // [NOUT]
    float* __restrict__ out)            // [T_TOK][NOUT]
{
  __shared__ __align__(16) int8_t Asm[BM * BK];
  __shared__ __align__(16) int8_t Bsm[BN * BK];

  const int tid  = threadIdx.x;
  const int lane = tid & 63;
  const int wid  = tid >> 6;
  const int wr = wid >> 1, wc = wid & 1;
  const int n0 = blockIdx.x * BN;   // n fastest: 8 n-tiles share token tile in L2
  const int t0 = blockIdx.y * BM;

  v16i acc[2][2] = {};

  for (int kk = 0; kk < NIN / BK; ++kk) {
    const int k0 = kk * BK;
    // stage A tile: 16KB = 1024 slots of 16B; 4 instrs/thread
#pragma unroll
    for (int p = 0; p < 4; ++p) {
      const int s = p * 256 + tid;          // linear LDS slot
      const int r = s >> 3;                 // row 0..127
      const int cs = s & 7;                 // stored chunk
      const int col = (cs ^ (r & 7)) << 4;  // pre-swizzled source column
      gload_lds16(A8 + (size_t)(t0 + r) * NIN + k0 + col, Asm + s * 16);
    }
#pragma unroll
    for (int p = 0; p < 4; ++p) {
      const int s = p * 256 + tid;
      const int r = s >> 3;
      const int cs = s & 7;
      const int col = (cs ^ (r & 7)) << 4;
      gload_lds16(W8 + (size_t)(n0 + r) * NIN + k0 + col, Bsm + s * 16);
    }
    __syncthreads();   // drains vmcnt (global_load_lds) before reads

#pragma unroll
    for (int ks = 0; ks < 4; ++ks) {
      const int c = ks * 2 + (lane >> 5);   // logical 16B k-chunk
      v4i af[2], bf[2];
#pragma unroll
      for (int mt = 0; mt < 2; ++mt) {
        const int r = wr * 64 + mt * 32 + (lane & 31);
        af[mt] = *(const v4i*)(Asm + ((r << 3) + (c ^ (r & 7))) * 16);
      }
#pragma unroll
      for (int nt = 0; nt < 2; ++nt) {
        const int r = wc * 64 + nt * 32 + (lane & 31);
        bf[nt] = *(const v4i*)(Bsm + ((r << 3) + (c ^ (r & 7))) * 16);
      }
#pragma unroll
      for (int mt = 0; mt < 2; ++mt)
#pragma unroll
        for (int nt = 0; nt < 2; ++nt)
          acc[mt][nt] = __builtin_amdgcn_mfma_i32_32x32x32_i8(
              af[mt], bf[nt], acc[mt][nt], 0, 0, 0);
    }
    __syncthreads();
  }

  // Epilogue: C/D 32x32 layout col = lane&31, row = (reg&3)+8*(reg>>2)+4*(lane>>5)
#pragma unroll
  for (int mt = 0; mt < 2; ++mt) {
    int   trow[16];
    float asc[16];
#pragma unroll
    for (int reg = 0; reg < 16; ++reg) {
      const int t = t0 + wr * 64 + mt * 32 + (reg & 3) + 8 * (reg >> 2) + 4 * (lane >> 5);
      trow[reg] = t;
      asc[reg] = ascale[t];
    }
#pragma unroll
    for (int nt = 0; nt < 2; ++nt) {
      const int n = n0 + wc * 64 + nt * 32 + (lane & 31);
      const float wsc = wclip[n] * (1.f / 127.f);
      const float bs  = bias[n];
#pragma unroll
      for (int reg = 0; reg < 16; ++reg)
        out[(size_t)trow[reg] * NOUT + n] =
            (float)acc[mt][nt][reg] * asc[reg] * wsc + bs;
    }
  }
}

// ---------------------------------------------------------------------------
extern "C" void kernel_launch(void* const* d_in, const int* in_sizes, int n_in,
                              void* d_out, int out_size, void* d_ws, size_t ws_size,
                              hipStream_t stream) {
  const float* x      = (const float*)d_in[0];                 // [8,4096,1024] f32
  const int*   weight = (const int*)d_in[1];                   // int8 ref -> int32 buf
  const float* bias   = (const float*)d_in[2];                 // [1024]
  const float* wclip  = (const float*)d_in[3];                 // [1024]
  const float* sq     = (const float*)d_in[4];                 // [1024]
  float* out = (float*)d_out;

  // ws layout: x_int8 [32768*1024 B] | ascale [32768*4 B] | w8 [1024*1024 B]
  // requires ws_size >= ~34.7 MB
  uint8_t* ws = (uint8_t*)d_ws;
  uint32_t* xq     = (uint32_t*)ws;
  float*    asc    = (float*)(ws + (size_t)T_TOK * NIN);
  uint32_t* w8     = (uint32_t*)(ws + (size_t)T_TOK * NIN + (size_t)T_TOK * 4);

  repack_w<<<(NOUT * NIN / 4) / 256, 256, 0, stream>>>(weight, w8);
  quant<<<T_TOK / 4, 256, 0, stream>>>(x, sq, xq, asc);
  dim3 grid(NOUT / BN, T_TOK / BM);
  w8a8_gemm<<<grid, 256, 0, stream>>>((const int8_t*)xq, (const int8_t*)w8,
                                      asc, wclip, bias, out);
}

// Round 2
// 92.099 us; speedup vs baseline: 1.1582x; 1.1582x over previous
//
#include <hip/hip_runtime.h>
#include <stdint.h>

// Problem: out[t][n] = (sum_k q8(x[t]/sq)[k] * w8[n][k]) * a_scale[t] * (wclip[n]/127) + bias[n]
// B=8,S=4096 -> 32768 tokens, IN=OUT=1024.
#define T_TOK 32768
#define NIN   1024
#define NOUT  1024
#define BM    32      // tokens per block; block covers ALL 1024 outputs
#define NTHR  512     // 8 waves; wave w owns n-tiles w*4..w*4+3 (128 n)

typedef int v4i  __attribute__((ext_vector_type(4)));
typedef int v16i __attribute__((ext_vector_type(16)));

// ---------------------------------------------------------------------------
// K0: repack weight (arrives int32 [NOUT][NIN]) into MFMA-fragment order:
//   wf[(((nt*32 + ks)*64 + lane)*16 + j] = (int8) W[nt*32+(lane&31)][ks*32+(lane>>5)*16+j]
// so a wave's B-fragment load for (nt,ks) is one coalesced global_load_dwordx4
// at base + lane*16. One-time cost, 4 MB read / 1 MB write.
// ---------------------------------------------------------------------------
__global__ __launch_bounds__(256) void repack_w_frag(const int* __restrict__ w,
                                                     uint32_t* __restrict__ wf) {
  const int gid  = blockIdx.x * 256 + threadIdx.x;  // 65536 threads, 16B each
  const int lane = gid & 63;
  const int ks   = (gid >> 6) & 31;
  const int nt   = gid >> 11;
  const int n    = nt * 32 + (lane & 31);
  const int kb   = ks * 32 + (lane >> 5) * 16;
  const int* src = w + (size_t)n * NIN + kb;
  uint32_t d[4];
#pragma unroll
  for (int q = 0; q < 4; ++q) {
    const int4 v = ((const int4*)src)[q];
    d[q] = (uint32_t)(v.x & 0xff) | ((uint32_t)(v.y & 0xff) << 8) |
           ((uint32_t)(v.z & 0xff) << 16) | ((uint32_t)(v.w & 0xff) << 24);
  }
  ((uint4*)wf)[gid] = make_uint4(d[0], d[1], d[2], d[3]);
}

// ---------------------------------------------------------------------------
// K1: fused smoothquant + per-token int8 quant + int8 GEMM + dequant + bias.
// LDS: A8[32][1024] int8, 16B-chunk XOR-swizzled (chunk' = chunk ^ (row&7)) so
// MFMA A-fragment ds_read_b128 (32 lanes = 32 rows, fixed chunk) is
// bank-conflict-free (G4: row-major 1024B-stride rows all alias bank 0).
// K-loop has NO barriers: B-frags stream global->reg (depth-4 ring, static
// indices per rule #20), A-frags from read-only LDS.
// ---------------------------------------------------------------------------
__global__ __launch_bounds__(NTHR) void fused_w8a8(
    const float* __restrict__ x,      // [T_TOK][NIN]
    const uint8_t* __restrict__ wf,   // fragment-ordered weight, 1 MB
    const float* __restrict__ sq,     // [NIN]
    const float* __restrict__ wclip,  // [NOUT]
    const float* __restrict__ bias,   // [NOUT]
    float* __restrict__ out)          // [T_TOK][NOUT]
{
  __shared__ __align__(16) uint8_t A8[BM * NIN];
  __shared__ float ascale_s[BM];

  const int tid  = threadIdx.x;
  const int lane = tid & 63;
  const int w    = tid >> 6;
  const int t0   = blockIdx.x * BM;

  // ---------------- quant phase: wave w quantizes tokens w*4 .. w*4+3 -------
  // lane reads float4s at row-index lane + j*64 (coalesced 1KB/instr).
  const float4* sq4 = (const float4*)sq;
  float4 rs[4];
#pragma unroll
  for (int j = 0; j < 4; ++j) {
    const float4 s = sq4[j * 64 + lane];
    rs[j].x = __builtin_amdgcn_rcpf(s.x);
    rs[j].y = __builtin_amdgcn_rcpf(s.y);
    rs[j].z = __builtin_amdgcn_rcpf(s.z);
    rs[j].w = __builtin_amdgcn_rcpf(s.w);
  }
#pragma unroll
  for (int i = 0; i < 4; ++i) {
    const int tl = w * 4 + i;
    const float4* xr = (const float4*)(x + (size_t)(t0 + tl) * NIN);
    float4 v[4];
    float m = 0.f;
#pragma unroll
    for (int j = 0; j < 4; ++j) {
      float4 a = xr[j * 64 + lane];
      a.x *= rs[j].x; a.y *= rs[j].y; a.z *= rs[j].z; a.w *= rs[j].w;
      v[j] = a;
      m = fmaxf(m, fmaxf(fmaxf(fabsf(a.x), fabsf(a.y)),
                         fmaxf(fabsf(a.z), fabsf(a.w))));
    }
#pragma unroll
    for (int off = 1; off < 64; off <<= 1) m = fmaxf(m, __shfl_xor(m, off));
    const float as = fmaxf(m * (1.f / 127.f), 1e-8f);
    if (lane == 0) ascale_s[tl] = as;
    const float ia = __builtin_amdgcn_rcpf(as);
#pragma unroll
    for (int j = 0; j < 4; ++j) {
      const int q0 = (int)rintf(fminf(fmaxf(v[j].x * ia, -127.f), 127.f));
      const int q1 = (int)rintf(fminf(fmaxf(v[j].y * ia, -127.f), 127.f));
      const int q2 = (int)rintf(fminf(fmaxf(v[j].z * ia, -127.f), 127.f));
      const int q3 = (int)rintf(fminf(fmaxf(v[j].w * ia, -127.f), 127.f));
      const uint32_t d = (uint32_t)(q0 & 0xff) | ((uint32_t)(q1 & 0xff) << 8) |
                         ((uint32_t)(q2 & 0xff) << 16) | ((uint32_t)(q3 & 0xff) << 24);
      const int di = j * 64 + lane;                 // dword index in row (0..255)
      const int ch = (di >> 2) ^ (tl & 7);          // swizzled 16B chunk
      *(uint32_t*)(A8 + tl * NIN + ch * 16 + (di & 3) * 4) = d;
    }
  }
  __syncthreads();   // the ONLY barrier

  // ---------------- GEMM phase ---------------------------------------------
  v16i acc[4] = {};  // wave's 4 n-tiles of 32x32

  auto ldB = [&](int ks, int nt) -> v4i {
    return *(const v4i*)(wf +
        ((((size_t)(w * 4 + nt) * 32 + ks) * 64 + lane) << 4));
  };
  auto ldA = [&](int ks) -> v4i {
    const int row = lane & 31;
    const int ch  = (ks * 2 + (lane >> 5)) ^ (row & 7);
    return *(const v4i*)(A8 + row * NIN + ch * 16);
  };

  v4i B[4][4];  // [ring-slot][nt] — all indices compile-time (rule #20)
#pragma unroll
  for (int p = 0; p < 4; ++p)
#pragma unroll
    for (int nt = 0; nt < 4; ++nt) B[p][nt] = ldB(p, nt);

  for (int ks = 0; ks < 32; ks += 4) {
#pragma unroll
    for (int p = 0; p < 4; ++p) {
      const v4i af = ldA(ks + p);
#pragma unroll
      for (int nt = 0; nt < 4; ++nt)
        acc[nt] = __builtin_amdgcn_mfma_i32_32x32x32_i8(af, B[p][nt], acc[nt], 0, 0, 0);
      if (ks + 4 + p < 32) {
#pragma unroll
        for (int nt = 0; nt < 4; ++nt) B[p][nt] = ldB(ks + 4 + p, nt);
      }
    }
  }

  // ---------------- epilogue -----------------------------------------------
  // C/D 32x32 layout: col = lane&31 (n), row = (reg&3)+8*(reg>>2)+4*(lane>>5) (t)
#pragma unroll
  for (int nt = 0; nt < 4; ++nt) {
    const int n = (w * 4 + nt) * 32 + (lane & 31);
    const float wsc = wclip[n] * (1.f / 127.f);
    const float bs  = bias[n];
#pragma unroll
    for (int reg = 0; reg < 16; ++reg) {
      const int r = (reg & 3) + 8 * (reg >> 2) + 4 * (lane >> 5);
      out[(size_t)(t0 + r) * NOUT + n] =
          (float)acc[nt][reg] * ascale_s[r] * wsc + bs;
    }
  }
}

// ---------------------------------------------------------------------------
extern "C" void kernel_launch(void* const* d_in, const int* in_sizes, int n_in,
                              void* d_out, int out_size, void* d_ws, size_t ws_size,
                              hipStream_t stream) {
  const float* x      = (const float*)d_in[0];
  const int*   weight = (const int*)d_in[1];
  const float* bias   = (const float*)d_in[2];
  const float* wclip  = (const float*)d_in[3];
  const float* sq     = (const float*)d_in[4];
  float* out = (float*)d_out;

  uint32_t* wfrag = (uint32_t*)d_ws;   // 1 MB fragment-ordered weight

  repack_w_frag<<<(NOUT * NIN / 16) / 256, 256, 0, stream>>>(weight, wfrag);
  fused_w8a8<<<T_TOK / BM, NTHR, 0, stream>>>(x, (const uint8_t*)wfrag,
                                              sq, wclip, bias, out);
}

// Round 3
// 80.046 us; speedup vs baseline: 1.3325x; 1.1506x over previous
//
#include <hip/hip_runtime.h>
#include <stdint.h>

// out[t][n] = (sum_k q8(x[t]/sq)[k] * w8[n][k]) * a_scale[t] * (wclip[n]/127) + bias[n]
#define T_TOK 32768
#define NIN   1024
#define NOUT  1024
#define BM    64      // tokens per block; block covers ALL 1024 outputs
#define NTHR  1024    // 16 waves; wave w owns n in [w*64, w*64+64), all 64 tokens

typedef int v4i  __attribute__((ext_vector_type(4)));
typedef int v16i __attribute__((ext_vector_type(16)));

// ---------------------------------------------------------------------------
// K0: repack weight (int32 [NOUT][NIN]) into MFMA fragment order:
//   chunk(nt,ks,lane) = (nt*32 + ks)*64 + lane  (16 B each)
//   holding W[nt*32+(lane&31)][ks*32+(lane>>5)*16 .. +15] as int8.
// A wave's B-frag load is then one coalesced global_load_dwordx4 at
// base + lane*16.
// ---------------------------------------------------------------------------
__global__ __launch_bounds__(256) void repack_w_frag(const int* __restrict__ w,
                                                     uint32_t* __restrict__ wf) {
  const int gid  = blockIdx.x * 256 + threadIdx.x;  // 65536 chunks of 16B
  const int lane = gid & 63;
  const int ks   = (gid >> 6) & 31;
  const int nt   = gid >> 11;
  const int n    = nt * 32 + (lane & 31);
  const int kb   = ks * 32 + (lane >> 5) * 16;
  const int* src = w + (size_t)n * NIN + kb;
  uint32_t d[4];
#pragma unroll
  for (int q = 0; q < 4; ++q) {
    const int4 v = ((const int4*)src)[q];
    d[q] = (uint32_t)(v.x & 0xff) | ((uint32_t)(v.y & 0xff) << 8) |
           ((uint32_t)(v.z & 0xff) << 16) | ((uint32_t)(v.w & 0xff) << 24);
  }
  ((uint4*)wf)[gid] = make_uint4(d[0], d[1], d[2], d[3]);
}

// ---------------------------------------------------------------------------
// K1: fused quant + GEMM + dequant.
// LDS A is FRAGMENT-ordered with ks-XOR slot swizzle:
//   chunk(mt,ks,slot) = (mt*32+ks)*64 + (slot ^ (ks&7)),  slot = (t&31)+32*h
// Reads (ldA): lane l reads chunk base + (l ^ (ks&7)) -> permutation of 64
//   consecutive chunks -> conflict-free ds_read_b128.
// Writes (quant): chunk%8 = (t&7)^(ks&7); ks varies across lanes of one store
//   instruction -> all 8 bank groups covered -> conflict-free (2-way).
// ---------------------------------------------------------------------------
__global__ __launch_bounds__(NTHR, 1) void fused_w8a8(
    const float* __restrict__ x,      // [T_TOK][NIN]
    const uint8_t* __restrict__ wf,   // fragment-ordered weight, 1 MB
    const float* __restrict__ sq,     // [NIN]
    const float* __restrict__ wclip,  // [NOUT]
    const float* __restrict__ bias,   // [NOUT]
    float* __restrict__ asc_g,        // [T_TOK] scratch for per-token scales
    float* __restrict__ out)          // [T_TOK][NOUT]
{
  __shared__ __align__(16) uint8_t Af[BM * NIN];   // exactly 64 KiB

  const int tid  = threadIdx.x;
  const int lane = tid & 63;
  const int w    = tid >> 6;          // 0..15
  const int t0   = blockIdx.x * BM;

  // ---- prologue B prefetch (flies under the quant phase) -------------------
  const uint8_t* wfw = wf + (((size_t)w * 2) * 32 * 64) * 16;  // wave's nt0=2w
  auto ldB = [&](int ks, int j) -> v4i {
    return *(const v4i*)(wfw + ((((j * 32 + ks) * 64) + lane) << 4));
  };
  v4i Ba0 = ldB(0, 0), Ba1 = ldB(0, 1);
  v4i Bb0 = ldB(1, 0), Bb1 = ldB(1, 1);

  // ---- quant: wave w quantizes tokens w*4 .. w*4+3 -------------------------
  {
    const float4* sq4 = (const float4*)sq;
    float4 rs[4];
#pragma unroll
    for (int j = 0; j < 4; ++j) {
      const float4 s = sq4[j * 64 + lane];
      rs[j].x = __builtin_amdgcn_rcpf(s.x);
      rs[j].y = __builtin_amdgcn_rcpf(s.y);
      rs[j].z = __builtin_amdgcn_rcpf(s.z);
      rs[j].w = __builtin_amdgcn_rcpf(s.w);
    }
#pragma unroll
    for (int i = 0; i < 4; ++i) {
      const int tl = w * 4 + i;                       // 0..63
      const float4* xr = (const float4*)(x + (size_t)(t0 + tl) * NIN);
      float4 v[4];
      float m = 0.f;
#pragma unroll
      for (int j = 0; j < 4; ++j) {
        float4 a = xr[j * 64 + lane];
        a.x *= rs[j].x; a.y *= rs[j].y; a.z *= rs[j].z; a.w *= rs[j].w;
        v[j] = a;
        m = fmaxf(m, fmaxf(fmaxf(fabsf(a.x), fabsf(a.y)),
                           fmaxf(fabsf(a.z), fabsf(a.w))));
      }
#pragma unroll
      for (int off = 1; off < 64; off <<= 1) m = fmaxf(m, __shfl_xor(m, off));
      const float as = fmaxf(m * (1.f / 127.f), 1e-8f);
      if (lane == 0) asc_g[t0 + tl] = as;
      const float ia = __builtin_amdgcn_rcpf(as);
      const int mt = tl >> 5;
#pragma unroll
      for (int j = 0; j < 4; ++j) {
        const int q0 = (int)rintf(fminf(fmaxf(v[j].x * ia, -127.f), 127.f));
        const int q1 = (int)rintf(fminf(fmaxf(v[j].y * ia, -127.f), 127.f));
        const int q2 = (int)rintf(fminf(fmaxf(v[j].z * ia, -127.f), 127.f));
        const int q3 = (int)rintf(fminf(fmaxf(v[j].w * ia, -127.f), 127.f));
        const uint32_t d = (uint32_t)(q0 & 0xff) | ((uint32_t)(q1 & 0xff) << 8) |
                           ((uint32_t)(q2 & 0xff) << 16) | ((uint32_t)(q3 & 0xff) << 24);
        const int di  = j * 64 + lane;        // dword col index 0..255
        const int ksw = di >> 3;              // 16B chunk col 0..31
        const int h   = (di >> 2) & 1;
        const int slot = (tl & 31) + 32 * h;
        const int chunk = (mt * 32 + ksw) * 64 + (slot ^ (ksw & 7));
        *(uint32_t*)(Af + chunk * 16 + (di & 3) * 4) = d;
      }
    }
  }
  __syncthreads();   // the ONLY barrier

  // ---- GEMM: 32 K-steps, 4 MFMA each; B ring depth 2 (named, rule #20) -----
  auto ldA = [&](int mt, int ks) -> v4i {
    return *(const v4i*)(Af + ((((mt * 32 + ks) * 64) + (lane ^ (ks & 7))) << 4));
  };

  v16i acc00 = {}, acc01 = {}, acc10 = {}, acc11 = {};

  for (int ks = 0; ks < 32; ks += 2) {
    {
      const v4i a0 = ldA(0, ks), a1 = ldA(1, ks);
      __builtin_amdgcn_s_setprio(1);
      acc00 = __builtin_amdgcn_mfma_i32_32x32x32_i8(a0, Ba0, acc00, 0, 0, 0);
      acc01 = __builtin_amdgcn_mfma_i32_32x32x32_i8(a0, Ba1, acc01, 0, 0, 0);
      acc10 = __builtin_amdgcn_mfma_i32_32x32x32_i8(a1, Ba0, acc10, 0, 0, 0);
      acc11 = __builtin_amdgcn_mfma_i32_32x32x32_i8(a1, Ba1, acc11, 0, 0, 0);
      __builtin_amdgcn_s_setprio(0);
      if (ks + 2 < 32) { Ba0 = ldB(ks + 2, 0); Ba1 = ldB(ks + 2, 1); }
    }
    {
      const v4i a0 = ldA(0, ks + 1), a1 = ldA(1, ks + 1);
      __builtin_amdgcn_s_setprio(1);
      acc00 = __builtin_amdgcn_mfma_i32_32x32x32_i8(a0, Bb0, acc00, 0, 0, 0);
      acc01 = __builtin_amdgcn_mfma_i32_32x32x32_i8(a0, Bb1, acc01, 0, 0, 0);
      acc10 = __builtin_amdgcn_mfma_i32_32x32x32_i8(a1, Bb0, acc10, 0, 0, 0);
      acc11 = __builtin_amdgcn_mfma_i32_32x32x32_i8(a1, Bb1, acc11, 0, 0, 0);
      __builtin_amdgcn_s_setprio(0);
      if (ks + 3 < 32) { Bb0 = ldB(ks + 3, 0); Bb1 = ldB(ks + 3, 1); }
    }
  }

  // ---- epilogue: C/D layout col = lane&31, row = (reg&3)+8*(reg>>2)+4*(lane>>5)
  const int hr = 4 * (lane >> 5);
  const float* ascw = asc_g + t0;

#define EPI(ACC, MT, NTL)                                                    \
  do {                                                                       \
    const int n = w * 64 + (NTL) * 32 + (lane & 31);                         \
    const float wsc = wclip[n] * (1.f / 127.f);                              \
    const float bs  = bias[n];                                               \
    _Pragma("unroll")                                                        \
    for (int reg = 0; reg < 16; ++reg) {                                     \
      const int r = (MT) * 32 + (reg & 3) + 8 * (reg >> 2) + hr;             \
      out[(size_t)(t0 + r) * NOUT + n] =                                     \
          (float)ACC[reg] * ascw[r] * wsc + bs;                              \
    }                                                                        \
  } while (0)

  EPI(acc00, 0, 0);
  EPI(acc01, 0, 1);
  EPI(acc10, 1, 0);
  EPI(acc11, 1, 1);
#undef EPI
}

// ---------------------------------------------------------------------------
extern "C" void kernel_launch(void* const* d_in, const int* in_sizes, int n_in,
                              void* d_out, int out_size, void* d_ws, size_t ws_size,
                              hipStream_t stream) {
  const float* x      = (const float*)d_in[0];
  const int*   weight = (const int*)d_in[1];
  const float* bias   = (const float*)d_in[2];
  const float* wclip  = (const float*)d_in[3];
  const float* sq     = (const float*)d_in[4];
  float* out = (float*)d_out;

  // ws: wf (1 MB fragment-ordered weight) | asc_g (32768 floats = 128 KB)
  uint32_t* wfrag = (uint32_t*)d_ws;
  float*    asc_g = (float*)((uint8_t*)d_ws + (size_t)(NOUT / 32) * 32 * 64 * 16);

  repack_w_frag<<<(NOUT * NIN / 16) / 256, 256, 0, stream>>>(weight, wfrag);
  fused_w8a8<<<T_TOK / BM, NTHR, 0, stream>>>(x, (const uint8_t*)wfrag,
                                              sq, wclip, bias, asc_g, out);
}